// Round 1
// baseline (613.050 us; speedup 1.0000x reference)
//
#include <hip/hip_runtime.h>
#include <hip/hip_bf16.h>
#include <math.h>

#define D_MODEL 1024
#define NQKV    384     // 3*128
#define HS      128
#define TLEN    2048
#define NBATCH  8

// ---------------------------------------------------------------------------
// Kernel 1: qkv[n][h] = sum_d x[n][d] * W[h][d]
// M=16384, N=384, K=1024.  BM=BN=128, BK=16, 256 threads, 8x8 micro-tile.
// ---------------------------------------------------------------------------
__global__ __launch_bounds__(256) void qkv_gemm(const float* __restrict__ x,
                                                const float* __restrict__ W,
                                                float* __restrict__ qkv) {
    __shared__ float As[16][132];   // [k][m], pad 132 (16B-aligned rows)
    __shared__ float Bs[16][132];   // [k][n]

    const int tid  = threadIdx.x;
    const int row0 = blockIdx.x * 128;
    const int col0 = blockIdx.y * 128;
    const int tx   = tid & 15;
    const int ty   = tid >> 4;
    const int lr   = tid >> 2;          // 0..63
    const int lc   = (tid & 3) << 2;    // 0,4,8,12

    float acc[8][8];
#pragma unroll
    for (int i = 0; i < 8; ++i)
#pragma unroll
        for (int j = 0; j < 8; ++j) acc[i][j] = 0.f;

    for (int k0 = 0; k0 < D_MODEL; k0 += 16) {
        const float4 a0 = *(const float4*)&x[(size_t)(row0 + lr     ) * D_MODEL + k0 + lc];
        const float4 a1 = *(const float4*)&x[(size_t)(row0 + lr + 64) * D_MODEL + k0 + lc];
        const float4 b0 = *(const float4*)&W[(size_t)(col0 + lr     ) * D_MODEL + k0 + lc];
        const float4 b1 = *(const float4*)&W[(size_t)(col0 + lr + 64) * D_MODEL + k0 + lc];
        __syncthreads();   // previous iteration's reads done before overwrite
        As[lc + 0][lr]      = a0.x; As[lc + 1][lr]      = a0.y;
        As[lc + 2][lr]      = a0.z; As[lc + 3][lr]      = a0.w;
        As[lc + 0][lr + 64] = a1.x; As[lc + 1][lr + 64] = a1.y;
        As[lc + 2][lr + 64] = a1.z; As[lc + 3][lr + 64] = a1.w;
        Bs[lc + 0][lr]      = b0.x; Bs[lc + 1][lr]      = b0.y;
        Bs[lc + 2][lr]      = b0.z; Bs[lc + 3][lr]      = b0.w;
        Bs[lc + 0][lr + 64] = b1.x; Bs[lc + 1][lr + 64] = b1.y;
        Bs[lc + 2][lr + 64] = b1.z; Bs[lc + 3][lr + 64] = b1.w;
        __syncthreads();
#pragma unroll
        for (int k = 0; k < 16; ++k) {
            const float4 aA = *(const float4*)&As[k][ty * 8];
            const float4 aB = *(const float4*)&As[k][ty * 8 + 4];
            const float4 bA = *(const float4*)&Bs[k][tx * 8];
            const float4 bB = *(const float4*)&Bs[k][tx * 8 + 4];
            const float a[8] = {aA.x, aA.y, aA.z, aA.w, aB.x, aB.y, aB.z, aB.w};
            const float b[8] = {bA.x, bA.y, bA.z, bA.w, bB.x, bB.y, bB.z, bB.w};
#pragma unroll
            for (int i = 0; i < 8; ++i)
#pragma unroll
                for (int j = 0; j < 8; ++j) acc[i][j] += a[i] * b[j];
        }
    }
#pragma unroll
    for (int i = 0; i < 8; ++i) {
        const size_t r = (size_t)(row0 + ty * 8 + i);
        float4 c0 = {acc[i][0], acc[i][1], acc[i][2], acc[i][3]};
        float4 c1 = {acc[i][4], acc[i][5], acc[i][6], acc[i][7]};
        *(float4*)&qkv[r * NQKV + col0 + tx * 8]     = c0;
        *(float4*)&qkv[r * NQKV + col0 + tx * 8 + 4] = c1;
    }
}

// ---------------------------------------------------------------------------
// Kernel 2: causal flash attention.
// Block = (64-row Q tile, batch).  256 threads as 16x16:
//   thread (tx,ty) owns S[ty*4..+3][tx*4..+3] and O[ty*4..+3][tx*8..+7].
// ---------------------------------------------------------------------------
__global__ __launch_bounds__(256) void attn_fwd(const float* __restrict__ qkv,
                                                float* __restrict__ out) {
    __shared__ float Qs[64][132];
    __shared__ float Ks[64][132];
    __shared__ float Vs[64][132];
    __shared__ float Ps[64][65];

    const int tid = threadIdx.x;
    const int tx  = tid & 15;
    const int ty  = tid >> 4;
    const int qt  = blockIdx.x;          // 0..31
    const int b   = blockIdx.y;          // 0..7
    const int q0  = qt * 64;
    const size_t base = (size_t)b * TLEN * NQKV;
    const float scale = 0.08838834764831845f;   // 1/sqrt(128)

    // load Q tile (applies to whole kernel lifetime)
    for (int i = tid; i < 64 * 32; i += 256) {
        const int r  = i >> 5;
        const int c4 = (i & 31) << 2;
        *(float4*)&Qs[r][c4] =
            *(const float4*)&qkv[base + (size_t)(q0 + r) * NQKV + c4];
    }

    float m[4], l[4], acc[4][8];
#pragma unroll
    for (int ii = 0; ii < 4; ++ii) {
        m[ii] = -INFINITY;
        l[ii] = 0.f;
#pragma unroll
        for (int cc = 0; cc < 8; ++cc) acc[ii][cc] = 0.f;
    }

    for (int t = 0; t <= qt; ++t) {
        const int j0 = t * 64;
        // stage K,V tiles via registers (so the sync protects prior LDS reads)
        float4 kreg[8], vreg[8];
#pragma unroll
        for (int i = 0; i < 8; ++i) {
            const int idx = tid + i * 256;
            const int r   = idx >> 5;
            const int c4  = (idx & 31) << 2;
            kreg[i] = *(const float4*)&qkv[base + (size_t)(j0 + r) * NQKV + HS     + c4];
            vreg[i] = *(const float4*)&qkv[base + (size_t)(j0 + r) * NQKV + 2 * HS + c4];
        }
        __syncthreads();   // prior PV reads of Ks/Vs (and Q load at t=0) done
#pragma unroll
        for (int i = 0; i < 8; ++i) {
            const int idx = tid + i * 256;
            const int r   = idx >> 5;
            const int c4  = (idx & 31) << 2;
            *(float4*)&Ks[r][c4] = kreg[i];
            *(float4*)&Vs[r][c4] = vreg[i];
        }
        __syncthreads();

        // S = Q K^T (4x4 per thread)
        float s[4][4];
#pragma unroll
        for (int ii = 0; ii < 4; ++ii)
#pragma unroll
            for (int jj = 0; jj < 4; ++jj) s[ii][jj] = 0.f;
        for (int k = 0; k < HS; k += 4) {
            float4 q4[4], k4[4];
#pragma unroll
            for (int ii = 0; ii < 4; ++ii) q4[ii] = *(const float4*)&Qs[ty * 4 + ii][k];
#pragma unroll
            for (int jj = 0; jj < 4; ++jj) k4[jj] = *(const float4*)&Ks[tx * 4 + jj][k];
#pragma unroll
            for (int ii = 0; ii < 4; ++ii)
#pragma unroll
                for (int jj = 0; jj < 4; ++jj)
                    s[ii][jj] += q4[ii].x * k4[jj].x + q4[ii].y * k4[jj].y +
                                 q4[ii].z * k4[jj].z + q4[ii].w * k4[jj].w;
        }

        // online softmax (per row: reduce across the 16 lanes of the row group)
#pragma unroll
        for (int ii = 0; ii < 4; ++ii) {
            const int rg = q0 + ty * 4 + ii;
            float sv[4];
            float tm = -INFINITY;
#pragma unroll
            for (int jj = 0; jj < 4; ++jj) {
                const int jg = j0 + tx * 4 + jj;
                sv[jj] = (jg <= rg) ? s[ii][jj] * scale : -INFINITY;
                tm = fmaxf(tm, sv[jj]);
            }
#pragma unroll
            for (int off = 8; off >= 1; off >>= 1)
                tm = fmaxf(tm, __shfl_xor(tm, off, 16));
            const float newm  = fmaxf(m[ii], tm);
            const float alpha = expf(m[ii] - newm);
            float p[4];
            float rs = 0.f;
#pragma unroll
            for (int jj = 0; jj < 4; ++jj) {
                p[jj] = expf(sv[jj] - newm);
                rs += p[jj];
            }
#pragma unroll
            for (int off = 8; off >= 1; off >>= 1)
                rs += __shfl_xor(rs, off, 16);
            m[ii] = newm;
            l[ii] = l[ii] * alpha + rs;
#pragma unroll
            for (int cc = 0; cc < 8; ++cc) acc[ii][cc] *= alpha;
#pragma unroll
            for (int jj = 0; jj < 4; ++jj) Ps[ty * 4 + ii][tx * 4 + jj] = p[jj];
        }
        __syncthreads();

        // O += P @ V
        for (int kk = 0; kk < 64; ++kk) {
            const float4 vA = *(const float4*)&Vs[kk][tx * 8];
            const float4 vB = *(const float4*)&Vs[kk][tx * 8 + 4];
            const float vv[8] = {vA.x, vA.y, vA.z, vA.w, vB.x, vB.y, vB.z, vB.w};
#pragma unroll
            for (int ii = 0; ii < 4; ++ii) {
                const float p = Ps[ty * 4 + ii][kk];
#pragma unroll
                for (int cc = 0; cc < 8; ++cc) acc[ii][cc] += p * vv[cc];
            }
        }
    }

    // normalize + write
#pragma unroll
    for (int ii = 0; ii < 4; ++ii) {
        const float inv = 1.f / l[ii];
        float4 o0 = {acc[ii][0] * inv, acc[ii][1] * inv, acc[ii][2] * inv, acc[ii][3] * inv};
        float4 o1 = {acc[ii][4] * inv, acc[ii][5] * inv, acc[ii][6] * inv, acc[ii][7] * inv};
        const size_t o = ((size_t)b * TLEN + q0 + ty * 4 + ii) * HS + tx * 8;
        *(float4*)&out[o]     = o0;
        *(float4*)&out[o + 4] = o1;
    }
}

extern "C" void kernel_launch(void* const* d_in, const int* in_sizes, int n_in,
                              void* d_out, int out_size, void* d_ws, size_t ws_size,
                              hipStream_t stream) {
    const float* x = (const float*)d_in[0];      // (8,2048,1024) f32
    const float* W = (const float*)d_in[1];      // (384,1024) f32
    float* out = (float*)d_out;                  // (8,2048,128) f32
    float* qkv = (float*)d_ws;                   // 16384*384 f32 = 24 MB scratch

    dim3 g1(16384 / 128, NQKV / 128);            // (128, 3)
    qkv_gemm<<<g1, 256, 0, stream>>>(x, W, qkv);

    dim3 g2(TLEN / 64, NBATCH);                  // (32, 8)
    attn_fwd<<<g2, 256, 0, stream>>>(qkv, out);
}

// Round 2
// 106.966 us; speedup vs baseline: 5.7312x; 5.7312x over previous
//
#include <hip/hip_runtime.h>
#include <hip/hip_bf16.h>
#include <math.h>

#define D_MODEL 1024
#define TLEN    2048
#define NBATCH  8

typedef __attribute__((ext_vector_type(8))) short short8;
typedef __attribute__((ext_vector_type(4))) float f32x4;

static __device__ __forceinline__ unsigned short f2bf(float f) {
    __hip_bfloat16 h = __float2bfloat16(f);
    return __builtin_bit_cast(unsigned short, h);
}

// ---------------------------------------------------------------------------
// Kernel 1: qkv[n][h] = sum_d x[n][d] * W[h][d], bf16 MFMA.
// BM=64, BN=128, BK=32. Grid (256,3) = 768 blocks. 256 thr = 4 waves (2m x 2n),
// wave tile 32x64 -> 2x4 mfma tiles of 16x16x32.
// Epilogue: by<2 -> qk bf16 row-major [16384][256]; by==2 -> VT [8][128][2048].
// ---------------------------------------------------------------------------
__global__ __launch_bounds__(256) void qkv_gemm(const float* __restrict__ x,
                                                const float* __restrict__ W,
                                                unsigned short* __restrict__ qk,
                                                unsigned short* __restrict__ vt) {
    __shared__ unsigned short As[64][40];    // [m][k], stride 80B (16B mult)
    __shared__ unsigned short Bs[128][40];   // [h][k]

    const int tid  = threadIdx.x;
    const int lane = tid & 63;
    const int w    = tid >> 6;
    const int wm   = w >> 1, wn = w & 1;
    const int cc   = lane & 15, g = lane >> 4;
    const int row0 = blockIdx.x * 64;
    const int col0 = blockIdx.y * 128;

    const int sr = tid >> 2;          // 0..63
    const int sc = (tid & 3) * 8;     // 0,8,16,24

    const f32x4 zero = {0.f, 0.f, 0.f, 0.f};
    f32x4 acc[2][4];
#pragma unroll
    for (int i = 0; i < 2; ++i)
#pragma unroll
        for (int j = 0; j < 4; ++j) acc[i][j] = zero;

    for (int k0 = 0; k0 < D_MODEL; k0 += 32) {
        const float4 a0 = *(const float4*)&x[(size_t)(row0 + sr) * D_MODEL + k0 + sc];
        const float4 a1 = *(const float4*)&x[(size_t)(row0 + sr) * D_MODEL + k0 + sc + 4];
        const float4 b0 = *(const float4*)&W[(size_t)(col0 + sr) * D_MODEL + k0 + sc];
        const float4 b1 = *(const float4*)&W[(size_t)(col0 + sr) * D_MODEL + k0 + sc + 4];
        const float4 b2 = *(const float4*)&W[(size_t)(col0 + sr + 64) * D_MODEL + k0 + sc];
        const float4 b3 = *(const float4*)&W[(size_t)(col0 + sr + 64) * D_MODEL + k0 + sc + 4];
        __syncthreads();   // prior compute done reading LDS
        short8 av, bv0, bv1;
        av[0] = (short)f2bf(a0.x); av[1] = (short)f2bf(a0.y);
        av[2] = (short)f2bf(a0.z); av[3] = (short)f2bf(a0.w);
        av[4] = (short)f2bf(a1.x); av[5] = (short)f2bf(a1.y);
        av[6] = (short)f2bf(a1.z); av[7] = (short)f2bf(a1.w);
        bv0[0] = (short)f2bf(b0.x); bv0[1] = (short)f2bf(b0.y);
        bv0[2] = (short)f2bf(b0.z); bv0[3] = (short)f2bf(b0.w);
        bv0[4] = (short)f2bf(b1.x); bv0[5] = (short)f2bf(b1.y);
        bv0[6] = (short)f2bf(b1.z); bv0[7] = (short)f2bf(b1.w);
        bv1[0] = (short)f2bf(b2.x); bv1[1] = (short)f2bf(b2.y);
        bv1[2] = (short)f2bf(b2.z); bv1[3] = (short)f2bf(b2.w);
        bv1[4] = (short)f2bf(b3.x); bv1[5] = (short)f2bf(b3.y);
        bv1[6] = (short)f2bf(b3.z); bv1[7] = (short)f2bf(b3.w);
        *(short8*)&As[sr][sc]      = av;
        *(short8*)&Bs[sr][sc]      = bv0;
        *(short8*)&Bs[sr + 64][sc] = bv1;
        __syncthreads();

        short8 af[2], bf[4];
#pragma unroll
        for (int mt = 0; mt < 2; ++mt)
            af[mt] = *(const short8*)&As[wm * 32 + mt * 16 + cc][g * 8];
#pragma unroll
        for (int nt = 0; nt < 4; ++nt)
            bf[nt] = *(const short8*)&Bs[wn * 64 + nt * 16 + cc][g * 8];
#pragma unroll
        for (int mt = 0; mt < 2; ++mt)
#pragma unroll
            for (int nt = 0; nt < 4; ++nt)
                acc[mt][nt] = __builtin_amdgcn_mfma_f32_16x16x32_bf16(
                    af[mt], bf[nt], acc[mt][nt], 0, 0, 0);
    }

    if (blockIdx.y < 2) {
        // Q / K: bf16 row-major [16384][256]
#pragma unroll
        for (int mt = 0; mt < 2; ++mt)
#pragma unroll
            for (int nt = 0; nt < 4; ++nt)
#pragma unroll
                for (int r = 0; r < 4; ++r) {
                    const int row = row0 + wm * 32 + mt * 16 + g * 4 + r;
                    const int col = col0 + wn * 64 + nt * 16 + cc;
                    qk[(size_t)row * 256 + col] = f2bf(acc[mt][nt][r]);
                }
    } else {
        // V transposed: VT[b][d][t], packed 4-row (t-consecutive) 8B stores
        const int bb  = row0 >> 11;
        const int tr0 = row0 & 2047;
#pragma unroll
        for (int mt = 0; mt < 2; ++mt)
#pragma unroll
            for (int nt = 0; nt < 4; ++nt) {
                const int d    = wn * 64 + nt * 16 + cc;
                const int trow = tr0 + wm * 32 + mt * 16 + g * 4;
                ushort4 u;
                u.x = f2bf(acc[mt][nt][0]);
                u.y = f2bf(acc[mt][nt][1]);
                u.z = f2bf(acc[mt][nt][2]);
                u.w = f2bf(acc[mt][nt][3]);
                *(ushort4*)&vt[((size_t)(bb * 128 + d)) * TLEN + trow] = u;
            }
    }
}

// ---------------------------------------------------------------------------
// Kernel 2: causal flash attention, bf16 MFMA.
// Grid (32,8). Block = 256 thr = 4 waves, QBLK=64 (16 q-rows/wave), KVBLK=64.
// QK^T: symmetric-fragment trick. Softmax in C-layout (width-16 shfl).
// P -> per-wave LDS -> A-frag. V^T in LDS -> contiguous b128 B-frag.
// ---------------------------------------------------------------------------
__global__ __launch_bounds__(256) void attn_fwd(const unsigned short* __restrict__ qk,
                                                const unsigned short* __restrict__ vt,
                                                float* __restrict__ out) {
    __shared__ unsigned short Ks[64][136];     // [j][k], stride 272B
    __shared__ unsigned short Vs[128][72];     // [d][j], stride 144B
    __shared__ unsigned short Ps[4][16][72];   // per-wave [q][j]

    const int tid  = threadIdx.x;
    const int lane = tid & 63;
    const int w    = tid >> 6;
    const int cc   = lane & 15, g = lane >> 4;
    const int qt   = 31 - (int)blockIdx.x;     // long blocks first
    const int b    = blockIdx.y;
    const int q0   = qt * 64;
    const float scale = 0.08838834764831845f;  // 1/sqrt(128)

    // Q A-fragments, held in registers for the whole kernel
    short8 qf[4];
    {
        const unsigned short* qb =
            qk + ((size_t)(b * TLEN + q0 + w * 16 + cc)) * 256 + g * 8;
#pragma unroll
        for (int kt = 0; kt < 4; ++kt) qf[kt] = *(const short8*)(qb + kt * 32);
    }

    const f32x4 zero = {0.f, 0.f, 0.f, 0.f};
    f32x4 o[8];
#pragma unroll
    for (int nt = 0; nt < 8; ++nt) o[nt] = zero;
    float m[4] = {-INFINITY, -INFINITY, -INFINITY, -INFINITY};
    float l[4] = {0.f, 0.f, 0.f, 0.f};

    const int kr_row = tid >> 2;          // 0..63
    const int kr_c   = (tid & 3) * 32;    // 0..96
    const int vr_row = tid >> 1;          // 0..127
    const int vr_c   = (tid & 1) * 32;    // 0,32

    for (int t = 0; t <= qt; ++t) {
        const int j0 = t * 64;
        // reg-stage K (row-major, cols 128..255 of qk) and V^T tile
        short8 kr[4], vr[4];
        {
            const unsigned short* kg =
                qk + ((size_t)(b * TLEN + j0 + kr_row)) * 256 + 128 + kr_c;
            const unsigned short* vg =
                vt + ((size_t)(b * 128 + vr_row)) * TLEN + j0 + vr_c;
#pragma unroll
            for (int i = 0; i < 4; ++i) kr[i] = *(const short8*)(kg + i * 8);
#pragma unroll
            for (int i = 0; i < 4; ++i) vr[i] = *(const short8*)(vg + i * 8);
        }
        __syncthreads();
#pragma unroll
        for (int i = 0; i < 4; ++i) *(short8*)&Ks[kr_row][kr_c + i * 8] = kr[i];
#pragma unroll
        for (int i = 0; i < 4; ++i) *(short8*)&Vs[vr_row][vr_c + i * 8] = vr[i];
        __syncthreads();

        // S = Q K^T  (16 q-rows x 64 j per wave)
        f32x4 s[4];
#pragma unroll
        for (int jt = 0; jt < 4; ++jt) s[jt] = zero;
#pragma unroll
        for (int kt = 0; kt < 4; ++kt)
#pragma unroll
            for (int jt = 0; jt < 4; ++jt) {
                const short8 kf = *(const short8*)&Ks[jt * 16 + cc][kt * 32 + g * 8];
                s[jt] = __builtin_amdgcn_mfma_f32_16x16x32_bf16(qf[kt], kf, s[jt], 0, 0, 0);
            }

        const bool diag = (t == qt);
#pragma unroll
        for (int reg = 0; reg < 4; ++reg) {
            const int qrow = q0 + w * 16 + g * 4 + reg;
            float sv[4];
            float vmax = -INFINITY;
#pragma unroll
            for (int jt = 0; jt < 4; ++jt) {
                float v = s[jt][reg] * scale;
                if (diag && (j0 + jt * 16 + cc) > qrow) v = -INFINITY;
                sv[jt] = v;
                vmax   = fmaxf(vmax, v);
            }
#pragma unroll
            for (int off = 8; off >= 1; off >>= 1)
                vmax = fmaxf(vmax, __shfl_xor(vmax, off, 16));
            const float newm  = fmaxf(m[reg], vmax);
            const float alpha = __expf(m[reg] - newm);
            m[reg] = newm;
            float rs = 0.f;
#pragma unroll
            for (int jt = 0; jt < 4; ++jt) {
                const float p = __expf(sv[jt] - newm);
                rs += p;
                Ps[w][g * 4 + reg][jt * 16 + cc] = f2bf(p);
            }
#pragma unroll
            for (int off = 8; off >= 1; off >>= 1)
                rs += __shfl_xor(rs, off, 16);
            l[reg] = l[reg] * alpha + rs;
#pragma unroll
            for (int nt = 0; nt < 8; ++nt) o[nt][reg] *= alpha;
        }
        // wave-local P writes must land before cross-lane A-frag reads
        asm volatile("s_waitcnt lgkmcnt(0)" ::: "memory");

        // O += P V   (K-dim = 64 j, 2 steps of 32)
#pragma unroll
        for (int ks = 0; ks < 2; ++ks) {
            const short8 pa = *(const short8*)&Ps[w][cc][ks * 32 + g * 8];
#pragma unroll
            for (int nt = 0; nt < 8; ++nt) {
                const short8 vf = *(const short8*)&Vs[nt * 16 + cc][ks * 32 + g * 8];
                o[nt] = __builtin_amdgcn_mfma_f32_16x16x32_bf16(pa, vf, o[nt], 0, 0, 0);
            }
        }
    }

    float inv[4];
#pragma unroll
    for (int reg = 0; reg < 4; ++reg) inv[reg] = 1.f / l[reg];
#pragma unroll
    for (int nt = 0; nt < 8; ++nt)
#pragma unroll
        for (int reg = 0; reg < 4; ++reg)
            out[((size_t)(b * TLEN + q0 + w * 16 + g * 4 + reg)) * 128 + nt * 16 + cc] =
                o[nt][reg] * inv[reg];
}

extern "C" void kernel_launch(void* const* d_in, const int* in_sizes, int n_in,
                              void* d_out, int out_size, void* d_ws, size_t ws_size,
                              hipStream_t stream) {
    (void)in_sizes; (void)n_in; (void)out_size; (void)ws_size;
    const float* x = (const float*)d_in[0];      // (8,2048,1024) f32
    const float* W = (const float*)d_in[1];      // (384,1024) f32
    float* out = (float*)d_out;                  // (8,2048,128) f32

    unsigned short* qkbf = (unsigned short*)d_ws;              // [16384][256] bf16 (Q,K)
    unsigned short* vtbf = qkbf + (size_t)16384 * 256;         // [8][128][2048] bf16 (V^T)

    qkv_gemm<<<dim3(256, 3), 256, 0, stream>>>(x, W, qkbf, vtbf);
    attn_fwd<<<dim3(32, 8), 256, 0, stream>>>(qkbf, vtbf, out);
}

// Round 3
// 91.514 us; speedup vs baseline: 6.6990x; 1.1689x over previous
//
#include <hip/hip_runtime.h>
#include <hip/hip_bf16.h>
#include <math.h>

#define D_MODEL 1024
#define TLEN    2048

typedef __attribute__((ext_vector_type(8))) short short8;
typedef __attribute__((ext_vector_type(4))) float f32x4;

static __device__ __forceinline__ unsigned short f2bf(float f) {
    __hip_bfloat16 h = __float2bfloat16(f);
    return __builtin_bit_cast(unsigned short, h);
}

// ---------------------------------------------------------------------------
// Kernel 1: qkv = x @ W^T, bf16 MFMA.  BM=64, BN=384 (full), BK=32.
// Grid 256 blocks x 512 thr (8 waves, 2/SIMD). Wave w owns cols w*48..+47.
// x fetched exactly once (64 MB); W L2-resident. Prefetch k-step.
// Epilogue: cols<256 -> qk bf16 [16384][256]; cols>=256 -> VT[8][128][2048].
// ---------------------------------------------------------------------------
__global__ __launch_bounds__(512, 2) void qkv_gemm(const float* __restrict__ x,
                                                   const float* __restrict__ W,
                                                   unsigned short* __restrict__ qk,
                                                   unsigned short* __restrict__ vt) {
    __shared__ unsigned short As[64][40];    // [m][k] stride 80B
    __shared__ unsigned short Bs[384][40];   // [h][k]

    const int tid  = threadIdx.x;
    const int lane = tid & 63;
    const int w    = tid >> 6;               // 0..7
    const int cc   = lane & 15, g = lane >> 4;
    const int row0 = blockIdx.x * 64;

    const int xr = tid >> 3;                 // 0..63
    const int xc = (tid & 7) * 4;            // 0,4,..,28

    const f32x4 zero = {0.f, 0.f, 0.f, 0.f};
    f32x4 acc[4][3];
#pragma unroll
    for (int i = 0; i < 4; ++i)
#pragma unroll
        for (int j = 0; j < 3; ++j) acc[i][j] = zero;

    float4 xa, wb[6];
    xa = *(const float4*)&x[(size_t)(row0 + xr) * D_MODEL + xc];
#pragma unroll
    for (int i = 0; i < 6; ++i)
        wb[i] = *(const float4*)&W[(size_t)(xr + i * 64) * D_MODEL + xc];

    for (int k0 = 0; k0 < D_MODEL; k0 += 32) {
        __syncthreads();   // prior frag reads done
        {
            ushort4 u;
            u.x = f2bf(xa.x); u.y = f2bf(xa.y); u.z = f2bf(xa.z); u.w = f2bf(xa.w);
            *(ushort4*)&As[xr][xc] = u;
#pragma unroll
            for (int i = 0; i < 6; ++i) {
                ushort4 v;
                v.x = f2bf(wb[i].x); v.y = f2bf(wb[i].y);
                v.z = f2bf(wb[i].z); v.w = f2bf(wb[i].w);
                *(ushort4*)&Bs[xr + i * 64][xc] = v;
            }
        }
        __syncthreads();
        if (k0 + 32 < D_MODEL) {
            xa = *(const float4*)&x[(size_t)(row0 + xr) * D_MODEL + k0 + 32 + xc];
#pragma unroll
            for (int i = 0; i < 6; ++i)
                wb[i] = *(const float4*)&W[(size_t)(xr + i * 64) * D_MODEL + k0 + 32 + xc];
        }
        short8 af[4], bf[3];
#pragma unroll
        for (int mt = 0; mt < 4; ++mt)
            af[mt] = *(const short8*)&As[mt * 16 + cc][g * 8];
#pragma unroll
        for (int nt = 0; nt < 3; ++nt)
            bf[nt] = *(const short8*)&Bs[w * 48 + nt * 16 + cc][g * 8];
#pragma unroll
        for (int mt = 0; mt < 4; ++mt)
#pragma unroll
            for (int nt = 0; nt < 3; ++nt)
                acc[mt][nt] = __builtin_amdgcn_mfma_f32_16x16x32_bf16(
                    af[mt], bf[nt], acc[mt][nt], 0, 0, 0);
    }

    const int bb  = row0 >> 11;
    const int tr0 = row0 & 2047;
#pragma unroll
    for (int mt = 0; mt < 4; ++mt)
#pragma unroll
        for (int nt = 0; nt < 3; ++nt) {
            const int col0t = w * 48 + nt * 16;
            if (col0t < 256) {
#pragma unroll
                for (int r = 0; r < 4; ++r) {
                    const int row = row0 + mt * 16 + g * 4 + r;
                    qk[(size_t)row * 256 + col0t + cc] = f2bf(acc[mt][nt][r]);
                }
            } else {
                const int d    = col0t + cc - 256;
                const int trow = tr0 + mt * 16 + g * 4;
                ushort4 u;
                u.x = f2bf(acc[mt][nt][0]);
                u.y = f2bf(acc[mt][nt][1]);
                u.z = f2bf(acc[mt][nt][2]);
                u.w = f2bf(acc[mt][nt][3]);
                *(ushort4*)&vt[((size_t)(bb * 128 + d)) * TLEN + trow] = u;
            }
        }
}

// ---------------------------------------------------------------------------
// Kernel 2: causal flash attention, bf16 MFMA.
// Grid (32,8) x 512 thr = 8 waves. Waves 0-3 (group 0) take even KV tiles,
// waves 4-7 (group 1) take odd KV tiles of the SAME 64-row Q tile; partial
// (m,l,o) merged through LDS at the end. Prefetch next K/V under compute.
// ---------------------------------------------------------------------------
__global__ __launch_bounds__(512, 2) void attn_fwd(const unsigned short* __restrict__ qk,
                                                   const unsigned short* __restrict__ vt,
                                                   float* __restrict__ out) {
    __shared__ unsigned short Ks[2][64][136];
    __shared__ unsigned short Vs[2][128][72];
    __shared__ unsigned short Ps[8][16][72];
    __shared__ float Co[4][16][132];
    __shared__ float Cml[4][16][2];

    const int tid  = threadIdx.x;
    const int lane = tid & 63;
    const int w    = tid >> 6;       // 0..7
    const int gg   = w >> 2;         // KV-parity group
    const int wq   = w & 3;          // q sub-tile (16 rows)
    const int cc   = lane & 15, g = lane >> 4;
    const int qt   = 31 - (int)blockIdx.x;
    const int b    = blockIdx.y;
    const int q0   = qt * 64;
    const float scale = 0.08838834764831845f;  // 1/sqrt(128)

    const int gtid   = tid & 255;
    const int kr_row = gtid >> 2;        // 0..63
    const int kr_c   = (gtid & 3) * 32;  // 0..96
    const int vr_row = gtid >> 1;        // 0..127
    const int vr_c   = (gtid & 1) * 32;  // 0,32

    // Q A-fragments in registers for kernel lifetime
    short8 qf[4];
    {
        const unsigned short* qb =
            qk + ((size_t)(b * TLEN + q0 + wq * 16 + cc)) * 256 + g * 8;
#pragma unroll
        for (int kt = 0; kt < 4; ++kt) qf[kt] = *(const short8*)(qb + kt * 32);
    }

    const f32x4 zero = {0.f, 0.f, 0.f, 0.f};
    f32x4 o[8];
#pragma unroll
    for (int nt = 0; nt < 8; ++nt) o[nt] = zero;
    float m[4] = {-INFINITY, -INFINITY, -INFINITY, -INFINITY};
    float l[4] = {0.f, 0.f, 0.f, 0.f};

    const int n      = qt + 1;
    const int nsteps = (n + 1) >> 1;

    short8 kr[4], vr[4];
    const unsigned short* kbase = qk + ((size_t)(b * TLEN + kr_row)) * 256 + 128 + kr_c;
    const unsigned short* vbase = vt + ((size_t)(b * 128 + vr_row)) * TLEN + vr_c;

    {
        const int t0 = (gg < n) ? gg : (n - 1);
#pragma unroll
        for (int i = 0; i < 4; ++i) kr[i] = *(const short8*)(kbase + (size_t)t0 * 64 * 256 + i * 8);
#pragma unroll
        for (int i = 0; i < 4; ++i) vr[i] = *(const short8*)(vbase + t0 * 64 + i * 8);
    }

    for (int s = 0; s < nsteps; ++s) {
        const int  t      = 2 * s + gg;
        const bool active = (t < n);
        __syncthreads();   // prior step's LDS reads complete
#pragma unroll
        for (int i = 0; i < 4; ++i) *(short8*)&Ks[gg][kr_row][kr_c + i * 8] = kr[i];
#pragma unroll
        for (int i = 0; i < 4; ++i) *(short8*)&Vs[gg][vr_row][vr_c + i * 8] = vr[i];
        __syncthreads();
        if (s + 1 < nsteps) {
            int tn = 2 * (s + 1) + gg;
            if (tn > n - 1) tn = n - 1;
#pragma unroll
            for (int i = 0; i < 4; ++i) kr[i] = *(const short8*)(kbase + (size_t)tn * 64 * 256 + i * 8);
#pragma unroll
            for (int i = 0; i < 4; ++i) vr[i] = *(const short8*)(vbase + tn * 64 + i * 8);
        }
        if (active) {
            const int j0 = t * 64;
            // S = Q K^T
            f32x4 sreg[4];
#pragma unroll
            for (int jt = 0; jt < 4; ++jt) sreg[jt] = zero;
#pragma unroll
            for (int kt = 0; kt < 4; ++kt)
#pragma unroll
                for (int jt = 0; jt < 4; ++jt) {
                    const short8 kf = *(const short8*)&Ks[gg][jt * 16 + cc][kt * 32 + g * 8];
                    sreg[jt] = __builtin_amdgcn_mfma_f32_16x16x32_bf16(qf[kt], kf, sreg[jt], 0, 0, 0);
                }

            const bool diag = (t == qt);
#pragma unroll
            for (int reg = 0; reg < 4; ++reg) {
                const int qrow = q0 + wq * 16 + g * 4 + reg;
                float sv[4];
                float vmax = -INFINITY;
#pragma unroll
                for (int jt = 0; jt < 4; ++jt) {
                    float v = sreg[jt][reg] * scale;
                    if (diag && (j0 + jt * 16 + cc) > qrow) v = -INFINITY;
                    sv[jt] = v;
                    vmax   = fmaxf(vmax, v);
                }
#pragma unroll
                for (int off = 8; off >= 1; off >>= 1)
                    vmax = fmaxf(vmax, __shfl_xor(vmax, off, 16));
                const float newm  = fmaxf(m[reg], vmax);
                const float alpha = __expf(m[reg] - newm);
                m[reg] = newm;
                float rs = 0.f;
#pragma unroll
                for (int jt = 0; jt < 4; ++jt) {
                    const float p = __expf(sv[jt] - newm);
                    rs += p;
                    Ps[w][g * 4 + reg][jt * 16 + cc] = f2bf(p);
                }
#pragma unroll
                for (int off = 8; off >= 1; off >>= 1)
                    rs += __shfl_xor(rs, off, 16);
                l[reg] = l[reg] * alpha + rs;
#pragma unroll
                for (int nt = 0; nt < 8; ++nt) o[nt][reg] *= alpha;
            }
            // wave-local P writes must land before cross-lane A-frag reads
            asm volatile("s_waitcnt lgkmcnt(0)" ::: "memory");

            // O += P V
#pragma unroll
            for (int ks = 0; ks < 2; ++ks) {
                const short8 pa = *(const short8*)&Ps[w][cc][ks * 32 + g * 8];
#pragma unroll
                for (int nt = 0; nt < 8; ++nt) {
                    const short8 vf = *(const short8*)&Vs[gg][nt * 16 + cc][ks * 32 + g * 8];
                    o[nt] = __builtin_amdgcn_mfma_f32_16x16x32_bf16(pa, vf, o[nt], 0, 0, 0);
                }
            }
        }
    }

    // merge group 1's partial state into group 0, write out
    __syncthreads();
    if (gg == 1) {
#pragma unroll
        for (int nt = 0; nt < 8; ++nt)
#pragma unroll
            for (int reg = 0; reg < 4; ++reg)
                Co[wq][g * 4 + reg][nt * 16 + cc] = o[nt][reg];
        if (cc == 0) {
#pragma unroll
            for (int reg = 0; reg < 4; ++reg) {
                Cml[wq][g * 4 + reg][0] = m[reg];
                Cml[wq][g * 4 + reg][1] = l[reg];
            }
        }
    }
    __syncthreads();
    if (gg == 0) {
#pragma unroll
        for (int reg = 0; reg < 4; ++reg) {
            const int r  = g * 4 + reg;
            const float m1 = Cml[wq][r][0];
            const float l1 = Cml[wq][r][1];
            const float M  = fmaxf(m[reg], m1);
            const float e0 = __expf(m[reg] - M);
            const float e1 = __expf(m1 - M);
            const float inv = 1.f / (l[reg] * e0 + l1 * e1);
            const size_t row = (size_t)(b * TLEN + q0 + wq * 16 + r);
#pragma unroll
            for (int nt = 0; nt < 8; ++nt)
                out[row * 128 + nt * 16 + cc] =
                    (o[nt][reg] * e0 + Co[wq][r][nt * 16 + cc] * e1) * inv;
        }
    }
}

extern "C" void kernel_launch(void* const* d_in, const int* in_sizes, int n_in,
                              void* d_out, int out_size, void* d_ws, size_t ws_size,
                              hipStream_t stream) {
    (void)in_sizes; (void)n_in; (void)out_size; (void)ws_size;
    const float* x = (const float*)d_in[0];      // (8,2048,1024) f32
    const float* W = (const float*)d_in[1];      // (384,1024) f32
    float* out = (float*)d_out;                  // (8,2048,128) f32

    unsigned short* qkbf = (unsigned short*)d_ws;          // [16384][256] bf16 (Q,K)
    unsigned short* vtbf = qkbf + (size_t)16384 * 256;     // [8][128][2048] bf16 (V^T)

    qkv_gemm<<<dim3(256), 512, 0, stream>>>(x, W, qkbf, vtbf);
    attn_fwd<<<dim3(32, 8), 512, 0, stream>>>(qkbf, vtbf, out);
}

// Round 4
// 85.552 us; speedup vs baseline: 7.1659x; 1.0697x over previous
//
#include <hip/hip_runtime.h>
#include <hip/hip_bf16.h>
#include <math.h>

#define D_MODEL 1024
#define TLEN    2048

typedef __attribute__((ext_vector_type(8))) short short8;
typedef __attribute__((ext_vector_type(4))) float f32x4;

static __device__ __forceinline__ unsigned short f2bf(float f) {
    __hip_bfloat16 h = __float2bfloat16(f);
    return __builtin_bit_cast(unsigned short, h);
}

static __device__ __forceinline__ void lds_cp16(void* lds, const void* g) {
    __builtin_amdgcn_global_load_lds(
        (const __attribute__((address_space(1))) unsigned int*)g,
        (__attribute__((address_space(3))) unsigned int*)lds, 16, 0, 0);
}

// ---------------------------------------------------------------------------
// Kernel 0: pack W fp32 [384][1024] -> wt bf16 [np3][kt16][h128][k64],
// swizzled: 8-short k-group index kg XOR (h&7), so that a LINEAR copy into
// LDS + XOR-swizzled ds_read_b128 is bank-spread.
// ---------------------------------------------------------------------------
__global__ __launch_bounds__(256) void pack_w(const float* __restrict__ W,
                                              unsigned short* __restrict__ wt) {
    const int id = blockIdx.x * 256 + threadIdx.x;   // 49152 threads
    const int h  = id >> 7;          // 0..383
    const int kg = id & 127;         // 8-float group within row
    const int k0 = kg * 8;
    const int kt = k0 >> 6;          // 0..15
    const int kin = k0 & 63;         // multiple of 8
    const int np = h >> 7;
    const int hp = h & 127;
    const float4 a = *(const float4*)&W[(size_t)h * D_MODEL + k0];
    const float4 b = *(const float4*)&W[(size_t)h * D_MODEL + k0 + 4];
    short8 v;
    v[0] = (short)f2bf(a.x); v[1] = (short)f2bf(a.y);
    v[2] = (short)f2bf(a.z); v[3] = (short)f2bf(a.w);
    v[4] = (short)f2bf(b.x); v[5] = (short)f2bf(b.y);
    v[6] = (short)f2bf(b.z); v[7] = (short)f2bf(b.w);
    const size_t dst = ((size_t)(np * 16 + kt) * 128 + hp) * 64 + (kin ^ ((hp & 7) * 8));
    *(short8*)&wt[dst] = v;
}

// ---------------------------------------------------------------------------
// Kernel 1: qkv = x @ W^T, bf16 MFMA. BM=64, BN=128, BK=64. Grid (256,3),
// 256 thr = 4 waves (2m x 2n), wave tile 32x64 = 2x4 mfma 16x16x32, 2 k-subs.
// B staged via global_load_lds from pre-swizzled wt (no VALU, no regs).
// A (x fp32) converted inline, stride-88 LDS rows (conflict-free b128).
// ---------------------------------------------------------------------------
__global__ __launch_bounds__(256, 4) void qkv_gemm(const float* __restrict__ x,
                                                   const unsigned short* __restrict__ wt,
                                                   unsigned short* __restrict__ qk,
                                                   unsigned short* __restrict__ vt) {
    __shared__ unsigned short As[64][88];      // [m][k] stride 176B
    __shared__ unsigned short Bs[128 * 64];    // linear (pre-swizzled source)

    const int tid  = threadIdx.x;
    const int lane = tid & 63;
    const int w    = tid >> 6;                 // 0..3
    const int wm   = w >> 1, wn = w & 1;
    const int cc   = lane & 15, g = lane >> 4;
    const int row0 = blockIdx.x * 64;
    const int np   = blockIdx.y;               // 0..2

    const int xr  = tid >> 2;                  // 0..63
    const int xc0 = (tid & 3) * 16;            // 0,16,32,48

    const f32x4 zero = {0.f, 0.f, 0.f, 0.f};
    f32x4 acc[2][4];
#pragma unroll
    for (int i = 0; i < 2; ++i)
#pragma unroll
        for (int j = 0; j < 4; ++j) acc[i][j] = zero;

    const float* xrow = x + (size_t)(row0 + xr) * D_MODEL + xc0;
    float4 xa[4];
#pragma unroll
    for (int i = 0; i < 4; ++i) xa[i] = *(const float4*)(xrow + i * 4);

    // per-wave gload_lds chunk: wave w copies bytes [w*4096, w*4096+4096)
    const unsigned short* wtile0 =
        wt + (size_t)np * 16 * 128 * 64 + (w * 4 * 1024 + lane * 16) / 2;
    unsigned short* bdst = Bs + (w * 4 * 1024) / 2;

    for (int kt = 0; kt < 16; ++kt) {
        __syncthreads();   // prior frag reads done
        {
            short8 s0, s1;
            s0[0] = (short)f2bf(xa[0].x); s0[1] = (short)f2bf(xa[0].y);
            s0[2] = (short)f2bf(xa[0].z); s0[3] = (short)f2bf(xa[0].w);
            s0[4] = (short)f2bf(xa[1].x); s0[5] = (short)f2bf(xa[1].y);
            s0[6] = (short)f2bf(xa[1].z); s0[7] = (short)f2bf(xa[1].w);
            s1[0] = (short)f2bf(xa[2].x); s1[1] = (short)f2bf(xa[2].y);
            s1[2] = (short)f2bf(xa[2].z); s1[3] = (short)f2bf(xa[2].w);
            s1[4] = (short)f2bf(xa[3].x); s1[5] = (short)f2bf(xa[3].y);
            s1[6] = (short)f2bf(xa[3].z); s1[7] = (short)f2bf(xa[3].w);
            *(short8*)&As[xr][xc0]     = s0;
            *(short8*)&As[xr][xc0 + 8] = s1;
        }
        // B tile: 16 KB linear copy, 4 instrs/wave
        const unsigned short* wtk = wtile0 + (size_t)kt * 128 * 64;
#pragma unroll
        for (int i = 0; i < 4; ++i)
            lds_cp16(bdst + i * 512, wtk + i * 512);
        __syncthreads();   // drains vmcnt (gload_lds) + lgkm (As writes)

        short8 af[2][2], bf[2][4];
#pragma unroll
        for (int ks = 0; ks < 2; ++ks) {
#pragma unroll
            for (int mt = 0; mt < 2; ++mt)
                af[ks][mt] = *(const short8*)&As[wm * 32 + mt * 16 + cc][ks * 32 + g * 8];
#pragma unroll
            for (int nt = 0; nt < 4; ++nt) {
                const int h = wn * 64 + nt * 16 + cc;
                bf[ks][nt] = *(const short8*)&Bs[h * 64 + (((ks * 4 + g) ^ (h & 7)) << 3)];
            }
        }
        if (kt + 1 < 16) {
#pragma unroll
            for (int i = 0; i < 4; ++i)
                xa[i] = *(const float4*)(xrow + (kt + 1) * 64 + i * 4);
        }
#pragma unroll
        for (int ks = 0; ks < 2; ++ks)
#pragma unroll
            for (int mt = 0; mt < 2; ++mt)
#pragma unroll
                for (int nt = 0; nt < 4; ++nt)
                    acc[mt][nt] = __builtin_amdgcn_mfma_f32_16x16x32_bf16(
                        af[ks][mt], bf[ks][nt], acc[mt][nt], 0, 0, 0);
    }

    const int bb  = row0 >> 11;
    const int tr0 = row0 & 2047;
#pragma unroll
    for (int mt = 0; mt < 2; ++mt)
#pragma unroll
        for (int nt = 0; nt < 4; ++nt) {
            const int colp = wn * 64 + nt * 16;   // 0..112 within panel
            if (np < 2) {
#pragma unroll
                for (int r = 0; r < 4; ++r) {
                    const int row = row0 + wm * 32 + mt * 16 + g * 4 + r;
                    qk[(size_t)row * 256 + np * 128 + colp + cc] = f2bf(acc[mt][nt][r]);
                }
            } else {
                const int d    = colp + cc;
                const int trow = tr0 + wm * 32 + mt * 16 + g * 4;
                ushort4 u;
                u.x = f2bf(acc[mt][nt][0]);
                u.y = f2bf(acc[mt][nt][1]);
                u.z = f2bf(acc[mt][nt][2]);
                u.w = f2bf(acc[mt][nt][3]);
                *(ushort4*)&vt[((size_t)(bb * 128 + d)) * TLEN + trow] = u;
            }
        }
}

// ---------------------------------------------------------------------------
// Kernel 2: causal flash attention (unchanged from round 3: even/odd KV-tile
// wave groups, intra-block merge, K/V prefetch).
// ---------------------------------------------------------------------------
__global__ __launch_bounds__(512, 2) void attn_fwd(const unsigned short* __restrict__ qk,
                                                   const unsigned short* __restrict__ vt,
                                                   float* __restrict__ out) {
    __shared__ unsigned short Ks[2][64][136];
    __shared__ unsigned short Vs[2][128][72];
    __shared__ unsigned short Ps[8][16][72];
    __shared__ float Co[4][16][132];
    __shared__ float Cml[4][16][2];

    const int tid  = threadIdx.x;
    const int lane = tid & 63;
    const int w    = tid >> 6;
    const int gg   = w >> 2;
    const int wq   = w & 3;
    const int cc   = lane & 15, g = lane >> 4;
    const int qt   = 31 - (int)blockIdx.x;
    const int b    = blockIdx.y;
    const int q0   = qt * 64;
    const float scale = 0.08838834764831845f;

    const int gtid   = tid & 255;
    const int kr_row = gtid >> 2;
    const int kr_c   = (gtid & 3) * 32;
    const int vr_row = gtid >> 1;
    const int vr_c   = (gtid & 1) * 32;

    short8 qf[4];
    {
        const unsigned short* qb =
            qk + ((size_t)(b * TLEN + q0 + wq * 16 + cc)) * 256 + g * 8;
#pragma unroll
        for (int kt = 0; kt < 4; ++kt) qf[kt] = *(const short8*)(qb + kt * 32);
    }

    const f32x4 zero = {0.f, 0.f, 0.f, 0.f};
    f32x4 o[8];
#pragma unroll
    for (int nt = 0; nt < 8; ++nt) o[nt] = zero;
    float m[4] = {-INFINITY, -INFINITY, -INFINITY, -INFINITY};
    float l[4] = {0.f, 0.f, 0.f, 0.f};

    const int n      = qt + 1;
    const int nsteps = (n + 1) >> 1;

    short8 kr[4], vr[4];
    const unsigned short* kbase = qk + ((size_t)(b * TLEN + kr_row)) * 256 + 128 + kr_c;
    const unsigned short* vbase = vt + ((size_t)(b * 128 + vr_row)) * TLEN + vr_c;

    {
        const int t0 = (gg < n) ? gg : (n - 1);
#pragma unroll
        for (int i = 0; i < 4; ++i) kr[i] = *(const short8*)(kbase + (size_t)t0 * 64 * 256 + i * 8);
#pragma unroll
        for (int i = 0; i < 4; ++i) vr[i] = *(const short8*)(vbase + t0 * 64 + i * 8);
    }

    for (int s = 0; s < nsteps; ++s) {
        const int  t      = 2 * s + gg;
        const bool active = (t < n);
        __syncthreads();
#pragma unroll
        for (int i = 0; i < 4; ++i) *(short8*)&Ks[gg][kr_row][kr_c + i * 8] = kr[i];
#pragma unroll
        for (int i = 0; i < 4; ++i) *(short8*)&Vs[gg][vr_row][vr_c + i * 8] = vr[i];
        __syncthreads();
        if (s + 1 < nsteps) {
            int tn = 2 * (s + 1) + gg;
            if (tn > n - 1) tn = n - 1;
#pragma unroll
            for (int i = 0; i < 4; ++i) kr[i] = *(const short8*)(kbase + (size_t)tn * 64 * 256 + i * 8);
#pragma unroll
            for (int i = 0; i < 4; ++i) vr[i] = *(const short8*)(vbase + tn * 64 + i * 8);
        }
        if (active) {
            const int j0 = t * 64;
            f32x4 sreg[4];
#pragma unroll
            for (int jt = 0; jt < 4; ++jt) sreg[jt] = zero;
#pragma unroll
            for (int kt = 0; kt < 4; ++kt)
#pragma unroll
                for (int jt = 0; jt < 4; ++jt) {
                    const short8 kf = *(const short8*)&Ks[gg][jt * 16 + cc][kt * 32 + g * 8];
                    sreg[jt] = __builtin_amdgcn_mfma_f32_16x16x32_bf16(qf[kt], kf, sreg[jt], 0, 0, 0);
                }

            const bool diag = (t == qt);
#pragma unroll
            for (int reg = 0; reg < 4; ++reg) {
                const int qrow = q0 + wq * 16 + g * 4 + reg;
                float sv[4];
                float vmax = -INFINITY;
#pragma unroll
                for (int jt = 0; jt < 4; ++jt) {
                    float v = sreg[jt][reg] * scale;
                    if (diag && (j0 + jt * 16 + cc) > qrow) v = -INFINITY;
                    sv[jt] = v;
                    vmax   = fmaxf(vmax, v);
                }
#pragma unroll
                for (int off = 8; off >= 1; off >>= 1)
                    vmax = fmaxf(vmax, __shfl_xor(vmax, off, 16));
                const float newm  = fmaxf(m[reg], vmax);
                const float alpha = __expf(m[reg] - newm);
                m[reg] = newm;
                float rs = 0.f;
#pragma unroll
                for (int jt = 0; jt < 4; ++jt) {
                    const float p = __expf(sv[jt] - newm);
                    rs += p;
                    Ps[w][g * 4 + reg][jt * 16 + cc] = f2bf(p);
                }
#pragma unroll
                for (int off = 8; off >= 1; off >>= 1)
                    rs += __shfl_xor(rs, off, 16);
                l[reg] = l[reg] * alpha + rs;
#pragma unroll
                for (int nt = 0; nt < 8; ++nt) o[nt][reg] *= alpha;
            }
            asm volatile("s_waitcnt lgkmcnt(0)" ::: "memory");

#pragma unroll
            for (int ks = 0; ks < 2; ++ks) {
                const short8 pa = *(const short8*)&Ps[w][cc][ks * 32 + g * 8];
#pragma unroll
                for (int nt = 0; nt < 8; ++nt) {
                    const short8 vf = *(const short8*)&Vs[gg][nt * 16 + cc][ks * 32 + g * 8];
                    o[nt] = __builtin_amdgcn_mfma_f32_16x16x32_bf16(pa, vf, o[nt], 0, 0, 0);
                }
            }
        }
    }

    __syncthreads();
    if (gg == 1) {
#pragma unroll
        for (int nt = 0; nt < 8; ++nt)
#pragma unroll
            for (int reg = 0; reg < 4; ++reg)
                Co[wq][g * 4 + reg][nt * 16 + cc] = o[nt][reg];
        if (cc == 0) {
#pragma unroll
            for (int reg = 0; reg < 4; ++reg) {
                Cml[wq][g * 4 + reg][0] = m[reg];
                Cml[wq][g * 4 + reg][1] = l[reg];
            }
        }
    }
    __syncthreads();
    if (gg == 0) {
#pragma unroll
        for (int reg = 0; reg < 4; ++reg) {
            const int r  = g * 4 + reg;
            const float m1 = Cml[wq][r][0];
            const float l1 = Cml[wq][r][1];
            const float M  = fmaxf(m[reg], m1);
            const float e0 = __expf(m[reg] - M);
            const float e1 = __expf(m1 - M);
            const float inv = 1.f / (l[reg] * e0 + l1 * e1);
            const size_t row = (size_t)(b * TLEN + q0 + wq * 16 + r);
#pragma unroll
            for (int nt = 0; nt < 8; ++nt)
                out[row * 128 + nt * 16 + cc] =
                    (o[nt][reg] * e0 + Co[wq][r][nt * 16 + cc] * e1) * inv;
        }
    }
}

extern "C" void kernel_launch(void* const* d_in, const int* in_sizes, int n_in,
                              void* d_out, int out_size, void* d_ws, size_t ws_size,
                              hipStream_t stream) {
    (void)in_sizes; (void)n_in; (void)out_size; (void)ws_size;
    const float* x = (const float*)d_in[0];      // (8,2048,1024) f32
    const float* W = (const float*)d_in[1];      // (384,1024) f32
    float* out = (float*)d_out;                  // (8,2048,128) f32

    unsigned short* qkbf = (unsigned short*)d_ws;          // [16384][256] bf16
    unsigned short* vtbf = qkbf + (size_t)16384 * 256;     // [8][128][2048] bf16
    unsigned short* wtbf = vtbf + (size_t)8 * 128 * 2048;  // packed W, 768 KB

    pack_w<<<dim3(192), 256, 0, stream>>>(W, wtbf);
    qkv_gemm<<<dim3(256, 3), 256, 0, stream>>>(x, wtbf, qkbf, vtbf);
    attn_fwd<<<dim3(32, 8), 512, 0, stream>>>(qkbf, vtbf, out);
}